// Round 5
// baseline (220.250 us; speedup 1.0000x reference)
//
#include <hip/hip_runtime.h>
#include <math.h>

// Problem constants
constexpr int Bb = 8;     // batch
constexpr int Ns = 1024;  // tokens (32x32)
constexpr int Es = 256;   // embed
constexpr int NH = 8;     // heads
constexpr int DH = 32;    // head dim
constexpr int Mrows = Bb * Ns;        // 8192
constexpr int NX = Mrows * Es;        // 2097152

#define NBLK 512   // persistent grid: 2 blocks/CU x 256 CUs

typedef __bf16 bf16x8 __attribute__((ext_vector_type(8)));
typedef float  f32x4  __attribute__((ext_vector_type(4)));
union U4B8 { uint4 u; bf16x8 b; unsigned short s[8]; };

__device__ __forceinline__ unsigned short f2bf(float f) {
    union { float f; unsigned u; } c; c.f = f;
    unsigned r = (c.u + 0x7FFFu + ((c.u >> 16) & 1u)) >> 16;
    return (unsigned short)r;
}
__device__ __forceinline__ float bf2f(unsigned short h) {
    union { unsigned u; float f; } c; c.u = ((unsigned)h) << 16;
    return c.f;
}

// ---------------------------------------------------------------------------
// Device-scope grid barrier (all NBLK blocks co-resident by construction:
// __launch_bounds__(256,2) + 44.3KB LDS -> 2 blocks/CU x 256 CUs = 512).
// atomicAdd on global is device-scope [m20]; __threadfence = agent fence
// (cross-XCD release/acquire).
// ---------------------------------------------------------------------------
__device__ __forceinline__ void grid_barrier(unsigned* cnt, unsigned* gen) {
    __syncthreads();
    if (threadIdx.x == 0) {
        __threadfence();                       // release
        unsigned g = atomicAdd(gen, 0u);
        unsigned a = atomicAdd(cnt, 1u);
        if (a == NBLK - 1) {
            atomicExch(cnt, 0u);               // reset before gen bump
            atomicAdd(gen, 1u);
        } else {
            while (atomicAdd(gen, 0u) == g) { __builtin_amdgcn_s_sleep(2); }
        }
        __threadfence();                       // acquire
    }
    __syncthreads();
}

// Shared scratch (union of phase layouts), 16B aligned.
//  GEMM : As[64*72] + Ws[64*72] ushort = 36,864 B
//  Attn : S[32*228] f32 (29,184) + Pb[32*232] u16 (14,848) + Linv[32] (128) = 44,160 B
#define GLD 72
#define SST 228
#define PST 232
#define SMEM_BYTES 44288

// ---------------------------------------------------------------------------
// One 64x64 tile of C = A[.,256] @ W[.,256]^T + bias; A,W fp32 in global,
// cast to bf16 during LDS staging. 4 waves, wave = 2x2 MFMA 16x16x32, BK=64.
// MODE 0: qkv scatter -> qb (q/16), kb, vtb (transposed). MODE 1: fp32 out.
// ---------------------------------------------------------------------------
template<int MODE>
__device__ __forceinline__
void gemm_tile(const float* __restrict__ A, const float* __restrict__ W,
               const float* __restrict__ bias, int m0, int j0,
               unsigned short* As, unsigned short* Ws,
               unsigned short* qo, unsigned short* ko, unsigned short* vto,
               float* fo)
{
    const int t = threadIdx.x;
    const int srow = t >> 2;          // 0..63
    const int scol = (t & 3) * 16;    // 0,16,32,48

    const int lane = t & 63;
    const int wave = t >> 6;
    const int wm = (wave & 1) * 32;
    const int wn = (wave >> 1) * 32;
    const int fm = lane & 15;
    const int fq = lane >> 4;

    f32x4 acc[2][2];
    #pragma unroll
    for (int i = 0; i < 2; i++)
        #pragma unroll
        for (int j = 0; j < 2; j++)
            acc[i][j] = (f32x4){0.f, 0.f, 0.f, 0.f};

    const float* Arow = A + (size_t)(m0 + srow) * Es;
    const float* Wrow = W + (size_t)(j0 + srow) * Es;

    for (int k0 = 0; k0 < Es; k0 += 64) {
        float4 av[4], wv[4];
        #pragma unroll
        for (int i = 0; i < 4; i++) {
            av[i] = *(const float4*)(Arow + k0 + scol + 4 * i);
            wv[i] = *(const float4*)(Wrow + k0 + scol + 4 * i);
        }
        U4B8 pa0, pa1, pw0, pw1;
        #pragma unroll
        for (int i = 0; i < 2; i++) {
            pa0.s[4*i+0] = f2bf(av[i].x); pa0.s[4*i+1] = f2bf(av[i].y);
            pa0.s[4*i+2] = f2bf(av[i].z); pa0.s[4*i+3] = f2bf(av[i].w);
            pa1.s[4*i+0] = f2bf(av[i+2].x); pa1.s[4*i+1] = f2bf(av[i+2].y);
            pa1.s[4*i+2] = f2bf(av[i+2].z); pa1.s[4*i+3] = f2bf(av[i+2].w);
            pw0.s[4*i+0] = f2bf(wv[i].x); pw0.s[4*i+1] = f2bf(wv[i].y);
            pw0.s[4*i+2] = f2bf(wv[i].z); pw0.s[4*i+3] = f2bf(wv[i].w);
            pw1.s[4*i+0] = f2bf(wv[i+2].x); pw1.s[4*i+1] = f2bf(wv[i+2].y);
            pw1.s[4*i+2] = f2bf(wv[i+2].z); pw1.s[4*i+3] = f2bf(wv[i+2].w);
        }
        __syncthreads();   // previous tile/iter fully consumed
        *(uint4*)&As[srow * GLD + scol]     = pa0.u;
        *(uint4*)&As[srow * GLD + scol + 8] = pa1.u;
        *(uint4*)&Ws[srow * GLD + scol]     = pw0.u;
        *(uint4*)&Ws[srow * GLD + scol + 8] = pw1.u;
        __syncthreads();
        #pragma unroll
        for (int ks = 0; ks < 64; ks += 32) {
            U4B8 af0, af1, bf0, bf1;
            af0.u = *(const uint4*)&As[(wm +      fm) * GLD + ks + fq * 8];
            af1.u = *(const uint4*)&As[(wm + 16 + fm) * GLD + ks + fq * 8];
            bf0.u = *(const uint4*)&Ws[(wn +      fm) * GLD + ks + fq * 8];
            bf1.u = *(const uint4*)&Ws[(wn + 16 + fm) * GLD + ks + fq * 8];
            acc[0][0] = __builtin_amdgcn_mfma_f32_16x16x32_bf16(af0.b, bf0.b, acc[0][0], 0, 0, 0);
            acc[0][1] = __builtin_amdgcn_mfma_f32_16x16x32_bf16(af0.b, bf1.b, acc[0][1], 0, 0, 0);
            acc[1][0] = __builtin_amdgcn_mfma_f32_16x16x32_bf16(af1.b, bf0.b, acc[1][0], 0, 0, 0);
            acc[1][1] = __builtin_amdgcn_mfma_f32_16x16x32_bf16(af1.b, bf1.b, acc[1][1], 0, 0, 0);
        }
    }
    __syncthreads();   // tile done before LDS reused by caller's next tile

    // C/D mapping: col = lane&15, row = quad*4 + reg
    #pragma unroll
    for (int mt = 0; mt < 2; mt++) {
        #pragma unroll
        for (int nt = 0; nt < 2; nt++) {
            #pragma unroll
            for (int r = 0; r < 4; r++) {
                int row = m0 + wm + mt * 16 + fq * 4 + r;
                int col = j0 + wn + nt * 16 + fm;
                float val = acc[mt][nt][r] + bias[col];
                if (MODE == 0) {
                    int part = col >> 8;           // 0:q 1:k 2:v
                    int head = (col >> 5) & 7;
                    int d = col & 31;
                    int b = row >> 10;
                    int n = row & 1023;
                    int bh = b * NH + head;
                    if (part == 0)
                        qo[((size_t)bh * Ns + n) * DH + d] = f2bf(val * 0.0625f);
                    else if (part == 1)
                        ko[((size_t)bh * Ns + n) * DH + d] = f2bf(val);
                    else
                        vto[((size_t)bh * DH + d) * Ns + n] = f2bf(val);
                } else {
                    fo[(size_t)row * Es + col] = val;
                }
            }
        }
    }
}

// ---------------------------------------------------------------------------
// One attention unit (bh, hq): 224 contiguous keys, 28+28 MFMAs, LDS softmax.
// Writes ao fp32 [b][n][e].
// ---------------------------------------------------------------------------
__device__ __forceinline__
void attn_unit(const unsigned short* __restrict__ qb, const unsigned short* __restrict__ kb,
               const unsigned short* __restrict__ vtb, float* __restrict__ aob,
               int bh, int hq, float* S, unsigned short* Pb, float* Linv)
{
    const int t = threadIdx.x;
    const int lane = t & 63;
    const int w    = t >> 6;
    const int fm = lane & 15;
    const int fq = lane >> 4;

    int n0c = (hq - 3) * 32;
    n0c = n0c < 0 ? 0 : (n0c > Ns - 224 ? Ns - 224 : n0c);

    const int qbase = (w & 1) * 16;
    const int sel   = w >> 1;
    const int dbase = (w >> 1) * 16;

    // V^T fragment prefetch (B-operand: n=dim, k=key)
    const unsigned short* vrow = vtb + ((size_t)bh * DH + dbase + fm) * Ns;
    uint4 vpre[7];
    #pragma unroll
    for (int i = 0; i < 7; i++)
        vpre[i] = *(const uint4*)(vrow + n0c + i * 32 + fq * 8);

    // Q fragment (A-operand)
    U4B8 qa;
    qa.u = *(const uint4*)(qb + ((size_t)bh * Ns + hq * 32 + qbase + fm) * DH + fq * 8);

    // S = Q.K^T
    #pragma unroll
    for (int i = 0; i < 7; i++) {
        int kt = sel + 2 * i;
        U4B8 kf;
        kf.u = *(const uint4*)(kb + ((size_t)bh * Ns + n0c + kt * 16 + fm) * DH + fq * 8);
        f32x4 s = __builtin_amdgcn_mfma_f32_16x16x32_bf16(qa.b, kf.b, (f32x4){0.f,0.f,0.f,0.f}, 0, 0, 0);
        #pragma unroll
        for (int r = 0; r < 4; r++)
            S[(qbase + fq * 4 + r) * SST + kt * 16 + fm] = s[r];
    }
    __syncthreads();

    // masked softmax: 8 lanes per query, 28 keys each
    const int sq = t >> 3;
    const int l8 = t & 7;
    float sv[28];
    float smax = -INFINITY;
    #pragma unroll
    for (int i = 0; i < 28; i++) {
        int j = l8 + 8 * i;
        int g = n0c + j;
        int gh = g >> 5, gw = g & 31;
        int dh_ = gh - hq, dw_ = gw - sq;
        bool ok = (dh_ >= -3) && (dh_ <= 3) && (dw_ >= -5) && (dw_ <= 5);
        float x = ok ? S[sq * SST + j] : -INFINITY;
        sv[i] = x;
        smax = fmaxf(smax, x);
    }
    #pragma unroll
    for (int m = 1; m < 8; m <<= 1) smax = fmaxf(smax, __shfl_xor(smax, m));

    float lsum = 0.f;
    #pragma unroll
    for (int i = 0; i < 28; i++) {
        float p = __expf(sv[i] - smax);
        unsigned short pu = f2bf(p);
        Pb[sq * PST + l8 + 8 * i] = pu;
        lsum += bf2f(pu);
    }
    #pragma unroll
    for (int m = 1; m < 8; m <<= 1) lsum += __shfl_xor(lsum, m);
    if (l8 == 0) Linv[sq] = 1.f / lsum;
    __syncthreads();

    // O = P.V
    f32x4 acc = (f32x4){0.f, 0.f, 0.f, 0.f};
    #pragma unroll
    for (int i = 0; i < 7; i++) {
        U4B8 pa, vb;
        pa.u = *(const uint4*)&Pb[(qbase + fm) * PST + i * 32 + fq * 8];
        vb.u = vpre[i];
        acc = __builtin_amdgcn_mfma_f32_16x16x32_bf16(pa.b, vb.b, acc, 0, 0, 0);
    }

    const int b = bh >> 3, h = bh & 7;
    #pragma unroll
    for (int r = 0; r < 4; r++) {
        int qq = qbase + fq * 4 + r;
        aob[((size_t)(b * Ns) + hq * 32 + qq) * Es + h * DH + dbase + fm] = acc[r] * Linv[qq];
    }
    __syncthreads();   // protect S/Pb before next unit overwrites
}

// ---------------------------------------------------------------------------
// Fused persistent kernel: QKV gemm -> grid sync -> attention -> grid sync -> proj.
// ---------------------------------------------------------------------------
__global__ __launch_bounds__(256, 2)
void fused_wattn(const float* __restrict__ x, const float* __restrict__ qkv_w,
                 const float* __restrict__ qkv_b, const float* __restrict__ proj_w,
                 const float* __restrict__ proj_b,
                 unsigned short* __restrict__ qb, unsigned short* __restrict__ kb,
                 unsigned short* __restrict__ vtb, float* __restrict__ aob,
                 float* __restrict__ out, unsigned* __restrict__ bar)
{
    __shared__ __align__(16) char smem[SMEM_BYTES];
    unsigned short* As = (unsigned short*)smem;
    unsigned short* Ws = As + 64 * GLD;
    float* S  = (float*)smem;
    unsigned short* Pb = (unsigned short*)(smem + 29184);
    float* Linv = (float*)(smem + 44032);

    unsigned* cnt = bar;
    unsigned* gen = bar + 1;

    // Phase 1: QKV gemm, 1536 tiles (128 m x 12 n)
    for (int u = blockIdx.x; u < 1536; u += NBLK)
        gemm_tile<0>(x, qkv_w, qkv_b, (u & 127) * 64, (u >> 7) * 64,
                     As, Ws, qb, kb, vtb, nullptr);

    grid_barrier(cnt, gen);

    // Phase 2: attention, 2048 units (bh, hq)
    for (int u = blockIdx.x; u < 2048; u += NBLK)
        attn_unit(qb, kb, vtb, aob, u >> 5, u & 31, S, Pb, Linv);

    grid_barrier(cnt, gen);

    // Phase 3: proj gemm, 512 tiles (128 m x 4 n)
    for (int u = blockIdx.x; u < 512; u += NBLK)
        gemm_tile<1>(aob, proj_w, proj_b, (u & 127) * 64, (u >> 7) * 64,
                     As, Ws, nullptr, nullptr, nullptr, out);
}

extern "C" void kernel_launch(void* const* d_in, const int* in_sizes, int n_in,
                              void* d_out, int out_size, void* d_ws, size_t ws_size,
                              hipStream_t stream) {
    const float* x      = (const float*)d_in[0];  // [B,N,E]
    const float* qkv_w  = (const float*)d_in[1];  // [3E,E]
    const float* qkv_b  = (const float*)d_in[2];  // [3E]
    const float* proj_w = (const float*)d_in[3];  // [E,E]
    const float* proj_b = (const float*)d_in[4];  // [E]
    float* out = (float*)d_out;                   // [B,N,E]

    unsigned* bar = (unsigned*)d_ws;                              // 256 B region
    unsigned short* qb  = (unsigned short*)((char*)d_ws + 256);   // NX bf16
    unsigned short* kb  = qb + NX;
    unsigned short* vtb = kb + NX;
    float* aob = (float*)(vtb + NX);                              // NX fp32

    hipMemsetAsync(d_ws, 0, 256, stream);   // zero barrier state (capturable)
    fused_wattn<<<dim3(NBLK), dim3(256), 0, stream>>>(
        x, qkv_w, qkv_b, proj_w, proj_b, qb, kb, vtb, aob, out, bar);
}

// Round 6
// 109.268 us; speedup vs baseline: 2.0157x; 2.0157x over previous
//
#include <hip/hip_runtime.h>
#include <math.h>

// Problem constants
constexpr int Bb = 8;     // batch
constexpr int Ns = 1024;  // tokens (32x32)
constexpr int Es = 256;   // embed
constexpr int NH = 8;     // heads
constexpr int DH = 32;    // head dim
constexpr int Mrows = Bb * Ns;        // 8192
constexpr int NX = Mrows * Es;        // 2097152
constexpr int NP = Es * Es;           // 65536

typedef __bf16 bf16x8 __attribute__((ext_vector_type(8)));
typedef float  f32x4  __attribute__((ext_vector_type(4)));
union U4B8 { uint4 u; bf16x8 b; unsigned short s[8]; };

__device__ __forceinline__ unsigned short f2bf(float f) {
    union { float f; unsigned u; } c; c.f = f;
    unsigned r = (c.u + 0x7FFFu + ((c.u >> 16) & 1u)) >> 16;
    return (unsigned short)r;
}
__device__ __forceinline__ float bf2f(unsigned short h) {
    union { unsigned u; float f; } c; c.u = ((unsigned)h) << 16;
    return c.f;
}

#define GLD 72    // qkv-gemm LDS row stride (bf16)
#define SST 228   // S row stride (f32)
#define PST 232   // P row stride (bf16)
#define AOT 264   // attn-output LDS row stride (bf16); 528 B rows: 16B-aligned, 2-way banks

// ---------------------------------------------------------------------------
// Kernel 1: QKV GEMM, fp32 inputs cast to bf16 during LDS staging.
// Blocks 0..1535: 64x64 tile of [x @ qkv_w^T + b]; epilogue scatters
//   q*1/16 -> qo [bh][n][d], k -> ko [bh][n][d], v -> vto [bh][d][n]  (bf16).
// Blocks 1536..1599: cast proj_w fp32 -> bf16 (pwb).
// ---------------------------------------------------------------------------
__global__ __launch_bounds__(256, 4)
void qkv_gemm(const float* __restrict__ x, const float* __restrict__ qkv_w,
              const float* __restrict__ qkv_b, const float* __restrict__ proj_w,
              unsigned short* __restrict__ qo, unsigned short* __restrict__ ko,
              unsigned short* __restrict__ vto, unsigned short* __restrict__ pwb)
{
    __shared__ unsigned short As[64 * GLD];
    __shared__ unsigned short Ws[64 * GLD];

    const int t = threadIdx.x;

    if (blockIdx.x >= 1536) {   // proj_w cast tail: 64 blocks x 1024 elems
        int i = ((int)(blockIdx.x - 1536) * 256 + t) * 4;
        float4 f = *(const float4*)(proj_w + i);
        ushort4 u;
        u.x = f2bf(f.x); u.y = f2bf(f.y); u.z = f2bf(f.z); u.w = f2bf(f.w);
        *(ushort4*)(pwb + i) = u;
        return;
    }

    const int m0 = (blockIdx.x & 127) * 64;
    const int j0 = (blockIdx.x >> 7) * 64;

    const int srow = t >> 2;          // 0..63
    const int scol = (t & 3) * 16;    // 0,16,32,48

    const int lane = t & 63;
    const int wave = t >> 6;
    const int wm = (wave & 1) * 32;
    const int wn = (wave >> 1) * 32;
    const int fm = lane & 15;
    const int fq = lane >> 4;

    f32x4 acc[2][2];
    #pragma unroll
    for (int i = 0; i < 2; i++)
        #pragma unroll
        for (int j = 0; j < 2; j++)
            acc[i][j] = (f32x4){0.f, 0.f, 0.f, 0.f};

    const float* Arow = x + (size_t)(m0 + srow) * Es;
    const float* Wrow = qkv_w + (size_t)(j0 + srow) * Es;

    for (int k0 = 0; k0 < Es; k0 += 64) {
        float4 av[4], wv[4];
        #pragma unroll
        for (int i = 0; i < 4; i++) {
            av[i] = *(const float4*)(Arow + k0 + scol + 4 * i);
            wv[i] = *(const float4*)(Wrow + k0 + scol + 4 * i);
        }
        U4B8 pa0, pa1, pw0, pw1;
        #pragma unroll
        for (int i = 0; i < 2; i++) {
            pa0.s[4*i+0] = f2bf(av[i].x);   pa0.s[4*i+1] = f2bf(av[i].y);
            pa0.s[4*i+2] = f2bf(av[i].z);   pa0.s[4*i+3] = f2bf(av[i].w);
            pa1.s[4*i+0] = f2bf(av[i+2].x); pa1.s[4*i+1] = f2bf(av[i+2].y);
            pa1.s[4*i+2] = f2bf(av[i+2].z); pa1.s[4*i+3] = f2bf(av[i+2].w);
            pw0.s[4*i+0] = f2bf(wv[i].x);   pw0.s[4*i+1] = f2bf(wv[i].y);
            pw0.s[4*i+2] = f2bf(wv[i].z);   pw0.s[4*i+3] = f2bf(wv[i].w);
            pw1.s[4*i+0] = f2bf(wv[i+2].x); pw1.s[4*i+1] = f2bf(wv[i+2].y);
            pw1.s[4*i+2] = f2bf(wv[i+2].z); pw1.s[4*i+3] = f2bf(wv[i+2].w);
        }
        __syncthreads();
        *(uint4*)&As[srow * GLD + scol]     = pa0.u;
        *(uint4*)&As[srow * GLD + scol + 8] = pa1.u;
        *(uint4*)&Ws[srow * GLD + scol]     = pw0.u;
        *(uint4*)&Ws[srow * GLD + scol + 8] = pw1.u;
        __syncthreads();
        #pragma unroll
        for (int ks = 0; ks < 64; ks += 32) {
            U4B8 af0, af1, bf0, bf1;
            af0.u = *(const uint4*)&As[(wm +      fm) * GLD + ks + fq * 8];
            af1.u = *(const uint4*)&As[(wm + 16 + fm) * GLD + ks + fq * 8];
            bf0.u = *(const uint4*)&Ws[(wn +      fm) * GLD + ks + fq * 8];
            bf1.u = *(const uint4*)&Ws[(wn + 16 + fm) * GLD + ks + fq * 8];
            acc[0][0] = __builtin_amdgcn_mfma_f32_16x16x32_bf16(af0.b, bf0.b, acc[0][0], 0, 0, 0);
            acc[0][1] = __builtin_amdgcn_mfma_f32_16x16x32_bf16(af0.b, bf1.b, acc[0][1], 0, 0, 0);
            acc[1][0] = __builtin_amdgcn_mfma_f32_16x16x32_bf16(af1.b, bf0.b, acc[1][0], 0, 0, 0);
            acc[1][1] = __builtin_amdgcn_mfma_f32_16x16x32_bf16(af1.b, bf1.b, acc[1][1], 0, 0, 0);
        }
    }

    // C/D: col = lane&15, row = quad*4 + reg
    #pragma unroll
    for (int mt = 0; mt < 2; mt++) {
        #pragma unroll
        for (int nt = 0; nt < 2; nt++) {
            #pragma unroll
            for (int r = 0; r < 4; r++) {
                int row = m0 + wm + mt * 16 + fq * 4 + r;
                int col = j0 + wn + nt * 16 + fm;
                float val = acc[mt][nt][r] + qkv_b[col];
                int part = col >> 8;           // 0:q 1:k 2:v
                int head = (col >> 5) & 7;
                int d = col & 31;
                int b = row >> 10;
                int n = row & 1023;
                int bh = b * NH + head;
                if (part == 0)
                    qo[((size_t)bh * Ns + n) * DH + d] = f2bf(val * 0.0625f);
                else if (part == 1)
                    ko[((size_t)bh * Ns + n) * DH + d] = f2bf(val);
                else
                    vto[((size_t)bh * DH + d) * Ns + n] = f2bf(val);
            }
        }
    }
}

// ---------------------------------------------------------------------------
// Kernel 2: attention (all 8 heads of one (b, hq) token-row) + output proj.
// 256 blocks x 512 thr. Two 4-wave groups; group g runs heads {g, g+2, g+4, g+6}.
// Attention unit identical to R3/R4 (verified); O written bf16 into LDS aot.
// Then 8 waves compute out[32x256] = aot @ pwb^T + proj_b.
// ---------------------------------------------------------------------------
__global__ __launch_bounds__(512, 2)
void attn_proj(const unsigned short* __restrict__ qb, const unsigned short* __restrict__ kb,
               const unsigned short* __restrict__ vtb, const unsigned short* __restrict__ pwb,
               const float* __restrict__ proj_b, float* __restrict__ out)
{
    __shared__ float S2[2][32 * SST];              // 2 x 29184 B
    __shared__ unsigned short Pb2[2][32 * PST];    // 2 x 14848 B
    __shared__ float Linv2[2][32];
    __shared__ unsigned short aot[32 * AOT];       // 16896 B

    const int t  = threadIdx.x;
    const int g  = t >> 8;          // group 0/1
    const int tl = t & 255;
    const int hq = blockIdx.x & 31;
    const int b  = blockIdx.x >> 5;

    float* S  = S2[g];
    unsigned short* Pb = Pb2[g];
    float* Linv = Linv2[g];

    const int lane = tl & 63;
    const int w    = tl >> 6;
    const int fm = lane & 15;
    const int fq = lane >> 4;
    const int qbase = (w & 1) * 16;
    const int sel   = w >> 1;
    const int dbase = (w >> 1) * 16;

    int n0c = (hq - 3) * 32;
    n0c = n0c < 0 ? 0 : (n0c > Ns - 224 ? Ns - 224 : n0c);

    for (int hi = 0; hi < 4; hi++) {
        const int h  = g + 2 * hi;
        const int bh = b * NH + h;

        // V^T fragment prefetch (B-operand: n=dim, k=key)
        const unsigned short* vrow = vtb + ((size_t)bh * DH + dbase + fm) * Ns;
        uint4 vpre[7];
        #pragma unroll
        for (int i = 0; i < 7; i++)
            vpre[i] = *(const uint4*)(vrow + n0c + i * 32 + fq * 8);

        // Q fragment (A-operand)
        U4B8 qa;
        qa.u = *(const uint4*)(qb + ((size_t)bh * Ns + hq * 32 + qbase + fm) * DH + fq * 8);

        // S = Q.K^T
        #pragma unroll
        for (int i = 0; i < 7; i++) {
            int kt = sel + 2 * i;
            U4B8 kf;
            kf.u = *(const uint4*)(kb + ((size_t)bh * Ns + n0c + kt * 16 + fm) * DH + fq * 8);
            f32x4 s = __builtin_amdgcn_mfma_f32_16x16x32_bf16(qa.b, kf.b, (f32x4){0.f,0.f,0.f,0.f}, 0, 0, 0);
            #pragma unroll
            for (int r = 0; r < 4; r++)
                S[(qbase + fq * 4 + r) * SST + kt * 16 + fm] = s[r];
        }
        __syncthreads();   // both groups: equal barrier counts (lockstep-safe)

        // masked softmax: 8 lanes per query, 28 keys each
        const int sq = tl >> 3;
        const int l8 = tl & 7;
        float sv[28];
        float smax = -INFINITY;
        #pragma unroll
        for (int i = 0; i < 28; i++) {
            int j = l8 + 8 * i;
            int gg = n0c + j;
            int gh = gg >> 5, gw = gg & 31;
            int dh_ = gh - hq, dw_ = gw - sq;
            bool ok = (dh_ >= -3) && (dh_ <= 3) && (dw_ >= -5) && (dw_ <= 5);
            float xv = ok ? S[sq * SST + j] : -INFINITY;
            sv[i] = xv;
            smax = fmaxf(smax, xv);
        }
        #pragma unroll
        for (int m = 1; m < 8; m <<= 1) smax = fmaxf(smax, __shfl_xor(smax, m));

        float lsum = 0.f;
        #pragma unroll
        for (int i = 0; i < 28; i++) {
            float p = __expf(sv[i] - smax);
            unsigned short pu = f2bf(p);
            Pb[sq * PST + l8 + 8 * i] = pu;
            lsum += bf2f(pu);
        }
        #pragma unroll
        for (int m = 1; m < 8; m <<= 1) lsum += __shfl_xor(lsum, m);
        if (l8 == 0) Linv[sq] = 1.f / lsum;
        __syncthreads();

        // O = P.V  -> aot (bf16), cols h*32 + dbase + fm
        f32x4 acc = (f32x4){0.f, 0.f, 0.f, 0.f};
        #pragma unroll
        for (int i = 0; i < 7; i++) {
            U4B8 pa, vb;
            pa.u = *(const uint4*)&Pb[(qbase + fm) * PST + i * 32 + fq * 8];
            vb.u = vpre[i];
            acc = __builtin_amdgcn_mfma_f32_16x16x32_bf16(pa.b, vb.b, acc, 0, 0, 0);
        }
        #pragma unroll
        for (int r = 0; r < 4; r++) {
            int qq = qbase + fq * 4 + r;
            aot[qq * AOT + h * DH + dbase + fm] = f2bf(acc[r] * Linv[qq]);
        }
        __syncthreads();   // aot writes visible; S/Pb safe to reuse next unit
    }

    // ---- projection: out[32 x 256] = aot @ pwb^T + proj_b ----
    const int ww   = t >> 6;          // 8 waves
    const int col0 = ww * 32;
    const int pl   = t & 63;
    const int pfm  = pl & 15;
    const int pfq  = pl >> 4;

    f32x4 pacc[2][2];
    #pragma unroll
    for (int i = 0; i < 2; i++)
        #pragma unroll
        for (int j = 0; j < 2; j++)
            pacc[i][j] = (f32x4){0.f, 0.f, 0.f, 0.f};

    #pragma unroll
    for (int k0 = 0; k0 < Es; k0 += 32) {
        U4B8 a0, a1, b0, b1;
        a0.u = *(const uint4*)&aot[(pfm)      * AOT + k0 + pfq * 8];
        a1.u = *(const uint4*)&aot[(16 + pfm) * AOT + k0 + pfq * 8];
        b0.u = *(const uint4*)(pwb + (size_t)(col0 + pfm)      * Es + k0 + pfq * 8);
        b1.u = *(const uint4*)(pwb + (size_t)(col0 + 16 + pfm) * Es + k0 + pfq * 8);
        pacc[0][0] = __builtin_amdgcn_mfma_f32_16x16x32_bf16(a0.b, b0.b, pacc[0][0], 0, 0, 0);
        pacc[0][1] = __builtin_amdgcn_mfma_f32_16x16x32_bf16(a0.b, b1.b, pacc[0][1], 0, 0, 0);
        pacc[1][0] = __builtin_amdgcn_mfma_f32_16x16x32_bf16(a1.b, b0.b, pacc[1][0], 0, 0, 0);
        pacc[1][1] = __builtin_amdgcn_mfma_f32_16x16x32_bf16(a1.b, b1.b, pacc[1][1], 0, 0, 0);
    }

    const int rowbase = b * Ns + hq * 32;
    #pragma unroll
    for (int mt = 0; mt < 2; mt++) {
        #pragma unroll
        for (int nt = 0; nt < 2; nt++) {
            #pragma unroll
            for (int r = 0; r < 4; r++) {
                int row = rowbase + mt * 16 + pfq * 4 + r;
                int col = col0 + nt * 16 + pfm;
                out[(size_t)row * Es + col] = pacc[mt][nt][r] + proj_b[col];
            }
        }
    }
}

extern "C" void kernel_launch(void* const* d_in, const int* in_sizes, int n_in,
                              void* d_out, int out_size, void* d_ws, size_t ws_size,
                              hipStream_t stream) {
    const float* x      = (const float*)d_in[0];  // [B,N,E]
    const float* qkv_w  = (const float*)d_in[1];  // [3E,E]
    const float* qkv_b  = (const float*)d_in[2];  // [3E]
    const float* proj_w = (const float*)d_in[3];  // [E,E]
    const float* proj_b = (const float*)d_in[4];  // [E]
    float* out = (float*)d_out;                   // [B,N,E]

    unsigned short* qb  = (unsigned short*)d_ws;  // NX bf16 (q, scaled)
    unsigned short* kb  = qb + NX;                // NX bf16
    unsigned short* vtb = kb + NX;                // NX bf16 (transposed)
    unsigned short* pwb = vtb + NX;               // NP bf16 (proj_w)

    qkv_gemm<<<dim3(1600), dim3(256), 0, stream>>>(
        x, qkv_w, qkv_b, proj_w, qb, kb, vtb, pwb);

    attn_proj<<<dim3(Bb * 32), dim3(512), 0, stream>>>(
        qb, kb, vtb, pwb, proj_b, out);
}

// Round 7
// 104.866 us; speedup vs baseline: 2.1003x; 1.0420x over previous
//
#include <hip/hip_runtime.h>
#include <math.h>

// Problem constants
constexpr int Bb = 8;     // batch
constexpr int Ns = 1024;  // tokens (32x32)
constexpr int Es = 256;   // embed
constexpr int NH = 8;     // heads
constexpr int DH = 32;    // head dim
constexpr int Mrows = Bb * Ns;        // 8192
constexpr int NX = Mrows * Es;        // 2097152
constexpr int NP = Es * Es;           // 65536

typedef __bf16 bf16x8 __attribute__((ext_vector_type(8)));
typedef float  f32x4  __attribute__((ext_vector_type(4)));
union U4B8 { uint4 u; bf16x8 b; unsigned short s[8]; };

__device__ __forceinline__ unsigned short f2bf(float f) {
    union { float f; unsigned u; } c; c.f = f;
    unsigned r = (c.u + 0x7FFFu + ((c.u >> 16) & 1u)) >> 16;
    return (unsigned short)r;
}
__device__ __forceinline__ float bf2f(unsigned short h) {
    union { unsigned u; float f; } c; c.u = ((unsigned)h) << 16;
    return c.f;
}

#define GLD 72    // gemm LDS row stride (bf16)
#define PST 232   // P row stride (bf16); lanes fm/fm+8 alias 2-way only (free)

// ---------------------------------------------------------------------------
// Kernel 1: QKV GEMM (unchanged from R6 — measured-good). fp32 inputs cast to
// bf16 during LDS staging. Blocks 0..1535: 64x64 tile; epilogue scatters
// q*1/16 -> qo [bh][n][d], k -> ko [bh][n][d], v -> vto [bh][d][n] (bf16).
// Blocks 1536..1599: cast proj_w fp32 -> bf16 (pwb).
// ---------------------------------------------------------------------------
__global__ __launch_bounds__(256, 4)
void qkv_gemm(const float* __restrict__ x, const float* __restrict__ qkv_w,
              const float* __restrict__ qkv_b, const float* __restrict__ proj_w,
              unsigned short* __restrict__ qo, unsigned short* __restrict__ ko,
              unsigned short* __restrict__ vto, unsigned short* __restrict__ pwb)
{
    __shared__ unsigned short As[64 * GLD];
    __shared__ unsigned short Ws[64 * GLD];

    const int t = threadIdx.x;

    if (blockIdx.x >= 1536) {   // proj_w cast tail
        int i = ((int)(blockIdx.x - 1536) * 256 + t) * 4;
        float4 f = *(const float4*)(proj_w + i);
        ushort4 u;
        u.x = f2bf(f.x); u.y = f2bf(f.y); u.z = f2bf(f.z); u.w = f2bf(f.w);
        *(ushort4*)(pwb + i) = u;
        return;
    }

    const int m0 = (blockIdx.x & 127) * 64;
    const int j0 = (blockIdx.x >> 7) * 64;

    const int srow = t >> 2;
    const int scol = (t & 3) * 16;

    const int lane = t & 63;
    const int wave = t >> 6;
    const int wm = (wave & 1) * 32;
    const int wn = (wave >> 1) * 32;
    const int fm = lane & 15;
    const int fq = lane >> 4;

    f32x4 acc[2][2];
    #pragma unroll
    for (int i = 0; i < 2; i++)
        #pragma unroll
        for (int j = 0; j < 2; j++)
            acc[i][j] = (f32x4){0.f, 0.f, 0.f, 0.f};

    const float* Arow = x + (size_t)(m0 + srow) * Es;
    const float* Wrow = qkv_w + (size_t)(j0 + srow) * Es;

    for (int k0 = 0; k0 < Es; k0 += 64) {
        float4 av[4], wv[4];
        #pragma unroll
        for (int i = 0; i < 4; i++) {
            av[i] = *(const float4*)(Arow + k0 + scol + 4 * i);
            wv[i] = *(const float4*)(Wrow + k0 + scol + 4 * i);
        }
        U4B8 pa0, pa1, pw0, pw1;
        #pragma unroll
        for (int i = 0; i < 2; i++) {
            pa0.s[4*i+0] = f2bf(av[i].x);   pa0.s[4*i+1] = f2bf(av[i].y);
            pa0.s[4*i+2] = f2bf(av[i].z);   pa0.s[4*i+3] = f2bf(av[i].w);
            pa1.s[4*i+0] = f2bf(av[i+2].x); pa1.s[4*i+1] = f2bf(av[i+2].y);
            pa1.s[4*i+2] = f2bf(av[i+2].z); pa1.s[4*i+3] = f2bf(av[i+2].w);
            pw0.s[4*i+0] = f2bf(wv[i].x);   pw0.s[4*i+1] = f2bf(wv[i].y);
            pw0.s[4*i+2] = f2bf(wv[i].z);   pw0.s[4*i+3] = f2bf(wv[i].w);
            pw1.s[4*i+0] = f2bf(wv[i+2].x); pw1.s[4*i+1] = f2bf(wv[i+2].y);
            pw1.s[4*i+2] = f2bf(wv[i+2].z); pw1.s[4*i+3] = f2bf(wv[i+2].w);
        }
        __syncthreads();
        *(uint4*)&As[srow * GLD + scol]     = pa0.u;
        *(uint4*)&As[srow * GLD + scol + 8] = pa1.u;
        *(uint4*)&Ws[srow * GLD + scol]     = pw0.u;
        *(uint4*)&Ws[srow * GLD + scol + 8] = pw1.u;
        __syncthreads();
        #pragma unroll
        for (int ks = 0; ks < 64; ks += 32) {
            U4B8 af0, af1, bf0, bf1;
            af0.u = *(const uint4*)&As[(wm +      fm) * GLD + ks + fq * 8];
            af1.u = *(const uint4*)&As[(wm + 16 + fm) * GLD + ks + fq * 8];
            bf0.u = *(const uint4*)&Ws[(wn +      fm) * GLD + ks + fq * 8];
            bf1.u = *(const uint4*)&Ws[(wn + 16 + fm) * GLD + ks + fq * 8];
            acc[0][0] = __builtin_amdgcn_mfma_f32_16x16x32_bf16(af0.b, bf0.b, acc[0][0], 0, 0, 0);
            acc[0][1] = __builtin_amdgcn_mfma_f32_16x16x32_bf16(af0.b, bf1.b, acc[0][1], 0, 0, 0);
            acc[1][0] = __builtin_amdgcn_mfma_f32_16x16x32_bf16(af1.b, bf0.b, acc[1][0], 0, 0, 0);
            acc[1][1] = __builtin_amdgcn_mfma_f32_16x16x32_bf16(af1.b, bf1.b, acc[1][1], 0, 0, 0);
        }
    }

    #pragma unroll
    for (int mt = 0; mt < 2; mt++) {
        #pragma unroll
        for (int nt = 0; nt < 2; nt++) {
            #pragma unroll
            for (int r = 0; r < 4; r++) {
                int row = m0 + wm + mt * 16 + fq * 4 + r;
                int col = j0 + wn + nt * 16 + fm;
                float val = acc[mt][nt][r] + qkv_b[col];
                int part = col >> 8;
                int head = (col >> 5) & 7;
                int d = col & 31;
                int b = row >> 10;
                int n = row & 1023;
                int bh = b * NH + head;
                if (part == 0)
                    qo[((size_t)bh * Ns + n) * DH + d] = f2bf(val * 0.0625f);
                else if (part == 1)
                    ko[((size_t)bh * Ns + n) * DH + d] = f2bf(val);
                else
                    vto[((size_t)bh * DH + d) * Ns + n] = f2bf(val);
            }
        }
    }
}

// ---------------------------------------------------------------------------
// Kernel 2: MFMA attention, in-register softmax. One block per (bh, hq).
// S stays in C-layout registers; mask computed from lane arithmetic; row
// max/sum via shfl_xor within 16-lane fm-groups + tiny LDS cross-parity
// combine. Only P (bf16) round-trips LDS (needed for the A-frag transform).
// LDS ~15.4 KB -> ~6 blocks/CU (vs 3 in R4). Writes aob bf16 [b][n][E].
// ---------------------------------------------------------------------------
__global__ __launch_bounds__(256)
void attn_mfma2(const unsigned short* __restrict__ qb, const unsigned short* __restrict__ kb,
                const unsigned short* __restrict__ vtb, unsigned short* __restrict__ aob)
{
    __shared__ unsigned short Pb[32 * PST];   // 14848 B
    __shared__ float pmax[2][32];             // [key parity][query]
    __shared__ float psum[2][32];

    const int blk = blockIdx.x;          // 0..2047
    const int hq  = blk & 31;
    const int bh  = blk >> 5;
    const int t   = threadIdx.x;
    const int lane = t & 63;
    const int w    = t >> 6;
    const int fm = lane & 15;
    const int fq = lane >> 4;

    int n0c = (hq - 3) * 32;
    n0c = n0c < 0 ? 0 : (n0c > Ns - 224 ? Ns - 224 : n0c);

    const int qbase = (w & 1) * 16;      // query 16-tile
    const int sel   = w >> 1;            // key-tile parity
    const int dbase = (w >> 1) * 16;     // PV dim-tile

    // V^T fragment prefetch (B-operand: n=dim, k=key)
    const unsigned short* vrow = vtb + ((size_t)bh * DH + dbase + fm) * Ns;
    uint4 vpre[7];
    #pragma unroll
    for (int i = 0; i < 7; i++)
        vpre[i] = *(const uint4*)(vrow + n0c + i * 32 + fq * 8);

    // Q fragment (A-operand)
    U4B8 qa;
    qa.u = *(const uint4*)(qb + ((size_t)bh * Ns + hq * 32 + qbase + fm) * DH + fq * 8);

    // S = Q.K^T, kept in registers (C-layout: key = kt*16+fm, query = qbase+fq*4+r)
    f32x4 sv[7];
    #pragma unroll
    for (int i = 0; i < 7; i++) {
        int kt = sel + 2 * i;
        U4B8 kf;
        kf.u = *(const uint4*)(kb + ((size_t)bh * Ns + n0c + kt * 16 + fm) * DH + fq * 8);
        sv[i] = __builtin_amdgcn_mfma_f32_16x16x32_bf16(qa.b, kf.b, (f32x4){0.f,0.f,0.f,0.f}, 0, 0, 0);
    }

    // Inline window mask + per-query local max over this wave's 7 keys
    float mx[4] = {-INFINITY, -INFINITY, -INFINITY, -INFINITY};
    #pragma unroll
    for (int i = 0; i < 7; i++) {
        int g = n0c + (sel + 2 * i) * 16 + fm;     // absolute key token
        int gh = g >> 5, gw = g & 31;
        int dhh = gh - hq;
        bool okh = (dhh >= -3) && (dhh <= 3);
        #pragma unroll
        for (int r = 0; r < 4; r++) {
            int qc = qbase + fq * 4 + r;
            int dww = gw - qc;
            bool ok = okh && (dww >= -5) && (dww <= 5);
            float s = ok ? sv[i][r] : -INFINITY;
            sv[i][r] = s;
            mx[r] = fmaxf(mx[r], s);
        }
    }
    // reduce across the 16 lanes sharing fq (xor bits 0..3 stay in-group)
    #pragma unroll
    for (int r = 0; r < 4; r++)
        #pragma unroll
        for (int m = 1; m < 16; m <<= 1)
            mx[r] = fmaxf(mx[r], __shfl_xor(mx[r], m));
    if (fm == 0) {
        #pragma unroll
        for (int r = 0; r < 4; r++)
            pmax[sel][qbase + fq * 4 + r] = mx[r];
    }
    __syncthreads();

    float M[4];
    #pragma unroll
    for (int r = 0; r < 4; r++) {
        int qc = qbase + fq * 4 + r;
        M[r] = fmaxf(pmax[0][qc], pmax[1][qc]);
    }

    // exp, write P (bf16), local sum of rounded values
    float sm[4] = {0.f, 0.f, 0.f, 0.f};
    #pragma unroll
    for (int i = 0; i < 7; i++) {
        int kt = sel + 2 * i;
        #pragma unroll
        for (int r = 0; r < 4; r++) {
            float p = __expf(sv[i][r] - M[r]);     // -inf -> 0
            unsigned short pu = f2bf(p);
            Pb[(qbase + fq * 4 + r) * PST + kt * 16 + fm] = pu;
            sm[r] += bf2f(pu);
        }
    }
    #pragma unroll
    for (int r = 0; r < 4; r++)
        #pragma unroll
        for (int m = 1; m < 16; m <<= 1)
            sm[r] += __shfl_xor(sm[r], m);
    if (fm == 0) {
        #pragma unroll
        for (int r = 0; r < 4; r++)
            psum[sel][qbase + fq * 4 + r] = sm[r];
    }
    __syncthreads();   // P complete + psum visible

    // O = P.V
    f32x4 acc = (f32x4){0.f, 0.f, 0.f, 0.f};
    #pragma unroll
    for (int i = 0; i < 7; i++) {
        U4B8 pa, vb;
        pa.u = *(const uint4*)&Pb[(qbase + fm) * PST + i * 32 + fq * 8];
        vb.u = vpre[i];
        acc = __builtin_amdgcn_mfma_f32_16x16x32_bf16(pa.b, vb.b, acc, 0, 0, 0);
    }

    const int b = bh >> 3, h = bh & 7;
    #pragma unroll
    for (int r = 0; r < 4; r++) {
        int qq = qbase + fq * 4 + r;
        float inv = 1.f / (psum[0][qq] + psum[1][qq]);
        aob[((size_t)(b * Ns) + hq * 32 + qq) * Es + h * DH + dbase + fm] = f2bf(acc[r] * inv);
    }
}

// ---------------------------------------------------------------------------
// Kernel 3: proj GEMM, bf16 inputs (aob, pwb), fp32 out. 64x64 tile, BK=64.
// ---------------------------------------------------------------------------
__global__ __launch_bounds__(256, 4)
void proj_gemm(const unsigned short* __restrict__ A, const unsigned short* __restrict__ Wb,
               const float* __restrict__ bias, float* __restrict__ out)
{
    __shared__ unsigned short As[64 * GLD];
    __shared__ unsigned short Ws[64 * GLD];

    const int t = threadIdx.x;
    const int m0 = (blockIdx.x & 127) * 64;
    const int j0 = (blockIdx.x >> 7) * 64;

    const int srow = t >> 2;
    const int scol = (t & 3) * 16;

    const int lane = t & 63;
    const int wave = t >> 6;
    const int wm = (wave & 1) * 32;
    const int wn = (wave >> 1) * 32;
    const int fm = lane & 15;
    const int fq = lane >> 4;

    f32x4 acc[2][2];
    #pragma unroll
    for (int i = 0; i < 2; i++)
        #pragma unroll
        for (int j = 0; j < 2; j++)
            acc[i][j] = (f32x4){0.f, 0.f, 0.f, 0.f};

    const unsigned short* Arow = A + (size_t)(m0 + srow) * Es;
    const unsigned short* Wrow = Wb + (size_t)(j0 + srow) * Es;

    for (int k0 = 0; k0 < Es; k0 += 64) {
        uint4 a0 = *(const uint4*)(Arow + k0 + scol);
        uint4 a1 = *(const uint4*)(Arow + k0 + scol + 8);
        uint4 w0 = *(const uint4*)(Wrow + k0 + scol);
        uint4 w1 = *(const uint4*)(Wrow + k0 + scol + 8);
        __syncthreads();
        *(uint4*)&As[srow * GLD + scol]     = a0;
        *(uint4*)&As[srow * GLD + scol + 8] = a1;
        *(uint4*)&Ws[srow * GLD + scol]     = w0;
        *(uint4*)&Ws[srow * GLD + scol + 8] = w1;
        __syncthreads();
        #pragma unroll
        for (int ks = 0; ks < 64; ks += 32) {
            U4B8 af0, af1, bf0, bf1;
            af0.u = *(const uint4*)&As[(wm +      fm) * GLD + ks + fq * 8];
            af1.u = *(const uint4*)&As[(wm + 16 + fm) * GLD + ks + fq * 8];
            bf0.u = *(const uint4*)&Ws[(wn +      fm) * GLD + ks + fq * 8];
            bf1.u = *(const uint4*)&Ws[(wn + 16 + fm) * GLD + ks + fq * 8];
            acc[0][0] = __builtin_amdgcn_mfma_f32_16x16x32_bf16(af0.b, bf0.b, acc[0][0], 0, 0, 0);
            acc[0][1] = __builtin_amdgcn_mfma_f32_16x16x32_bf16(af0.b, bf1.b, acc[0][1], 0, 0, 0);
            acc[1][0] = __builtin_amdgcn_mfma_f32_16x16x32_bf16(af1.b, bf0.b, acc[1][0], 0, 0, 0);
            acc[1][1] = __builtin_amdgcn_mfma_f32_16x16x32_bf16(af1.b, bf1.b, acc[1][1], 0, 0, 0);
        }
    }

    #pragma unroll
    for (int mt = 0; mt < 2; mt++) {
        #pragma unroll
        for (int nt = 0; nt < 2; nt++) {
            #pragma unroll
            for (int r = 0; r < 4; r++) {
                int row = m0 + wm + mt * 16 + fq * 4 + r;
                int col = j0 + wn + nt * 16 + fm;
                out[(size_t)row * Es + col] = acc[mt][nt][r] + bias[col];
            }
        }
    }
}

extern "C" void kernel_launch(void* const* d_in, const int* in_sizes, int n_in,
                              void* d_out, int out_size, void* d_ws, size_t ws_size,
                              hipStream_t stream) {
    const float* x      = (const float*)d_in[0];  // [B,N,E]
    const float* qkv_w  = (const float*)d_in[1];  // [3E,E]
    const float* qkv_b  = (const float*)d_in[2];  // [3E]
    const float* proj_w = (const float*)d_in[3];  // [E,E]
    const float* proj_b = (const float*)d_in[4];  // [E]
    float* out = (float*)d_out;                   // [B,N,E]

    unsigned short* qb  = (unsigned short*)d_ws;  // NX bf16 (q, scaled)
    unsigned short* kb  = qb + NX;                // NX bf16
    unsigned short* vtb = kb + NX;                // NX bf16 (transposed)
    unsigned short* pwb = vtb + NX;               // NP bf16 (proj_w)
    unsigned short* aob = pwb + NP;               // NX bf16 (attn out, [b][n][E])

    qkv_gemm<<<dim3(1600), dim3(256), 0, stream>>>(
        x, qkv_w, qkv_b, proj_w, qb, kb, vtb, pwb);

    attn_mfma2<<<dim3(Bb * NH * 32), dim3(256), 0, stream>>>(qb, kb, vtb, aob);

    proj_gemm<<<dim3(Mrows / 64 * (Es / 64)), dim3(256), 0, stream>>>(
        aob, pwb, proj_b, out);
}

// Round 8
// 102.206 us; speedup vs baseline: 2.1550x; 1.0260x over previous
//
#include <hip/hip_runtime.h>
#include <math.h>

// Problem constants
constexpr int Bb = 8;     // batch
constexpr int Ns = 1024;  // tokens (32x32)
constexpr int Es = 256;   // embed
constexpr int NH = 8;     // heads
constexpr int DH = 32;    // head dim
constexpr int Mrows = Bb * Ns;        // 8192
constexpr int NX = Mrows * Es;        // 2097152
constexpr int NQ = 3 * Es * Es;       // 196608
constexpr int NP = Es * Es;           // 65536

typedef __bf16 bf16x8 __attribute__((ext_vector_type(8)));
typedef float  f32x4  __attribute__((ext_vector_type(4)));
union U4B8 { uint4 u; bf16x8 b; unsigned short s[8]; };

__device__ __forceinline__ unsigned short f2bf(float f) {
    union { float f; unsigned u; } c; c.f = f;
    unsigned r = (c.u + 0x7FFFu + ((c.u >> 16) & 1u)) >> 16;
    return (unsigned short)r;
}
__device__ __forceinline__ float bf2f(unsigned short h) {
    union { unsigned u; float f; } c; c.u = ((unsigned)h) << 16;
    return c.f;
}

#define GLD 72    // gemm LDS row stride (bf16)
#define PST 232   // P row stride (bf16)

// ---------------------------------------------------------------------------
// Kernel 0: cast x, qkv_w, proj_w fp32 -> bf16 once (x was previously re-cast
// 12x inside qkv staging, qkv_w 128x). 8 elems/thread.
// ---------------------------------------------------------------------------
__global__ __launch_bounds__(256)
void cast_all(const float* __restrict__ x, const float* __restrict__ wq,
              const float* __restrict__ wp, unsigned short* __restrict__ xb,
              unsigned short* __restrict__ wqb, unsigned short* __restrict__ wpb)
{
    int i = (blockIdx.x * 256 + threadIdx.x) * 8;
    const float* src; unsigned short* dst;
    if (i < NX)            { src = x  + i;             dst = xb  + i; }
    else if (i < NX + NQ)  { src = wq + (i - NX);      dst = wqb + (i - NX); }
    else                   { src = wp + (i - NX - NQ); dst = wpb + (i - NX - NQ); }
    float4 f0 = *(const float4*)src;
    float4 f1 = *(const float4*)(src + 4);
    U4B8 u;
    u.s[0] = f2bf(f0.x); u.s[1] = f2bf(f0.y); u.s[2] = f2bf(f0.z); u.s[3] = f2bf(f0.w);
    u.s[4] = f2bf(f1.x); u.s[5] = f2bf(f1.y); u.s[6] = f2bf(f1.z); u.s[7] = f2bf(f1.w);
    *(uint4*)dst = u.u;
}

// ---------------------------------------------------------------------------
// Kernel 1: QKV GEMM, pure bf16 inputs. 64x64 tile, BK=64, 4 waves x 2x2 MFMA.
// Epilogue scatters q*1/16 -> qo [bh][n][d], k -> ko [bh][n][d],
// v -> vto [bh][d][n] (bf16).
// ---------------------------------------------------------------------------
__global__ __launch_bounds__(256, 4)
void qkv_gemm(const unsigned short* __restrict__ A, const unsigned short* __restrict__ W,
              const float* __restrict__ qkv_b,
              unsigned short* __restrict__ qo, unsigned short* __restrict__ ko,
              unsigned short* __restrict__ vto)
{
    __shared__ unsigned short As[64 * GLD];
    __shared__ unsigned short Ws[64 * GLD];

    const int t = threadIdx.x;
    const int m0 = (blockIdx.x & 127) * 64;
    const int j0 = (blockIdx.x >> 7) * 64;

    const int srow = t >> 2;
    const int scol = (t & 3) * 16;

    const int lane = t & 63;
    const int wave = t >> 6;
    const int wm = (wave & 1) * 32;
    const int wn = (wave >> 1) * 32;
    const int fm = lane & 15;
    const int fq = lane >> 4;

    f32x4 acc[2][2];
    #pragma unroll
    for (int i = 0; i < 2; i++)
        #pragma unroll
        for (int j = 0; j < 2; j++)
            acc[i][j] = (f32x4){0.f, 0.f, 0.f, 0.f};

    const unsigned short* Arow = A + (size_t)(m0 + srow) * Es;
    const unsigned short* Wrow = W + (size_t)(j0 + srow) * Es;

    for (int k0 = 0; k0 < Es; k0 += 64) {
        uint4 a0 = *(const uint4*)(Arow + k0 + scol);
        uint4 a1 = *(const uint4*)(Arow + k0 + scol + 8);
        uint4 w0 = *(const uint4*)(Wrow + k0 + scol);
        uint4 w1 = *(const uint4*)(Wrow + k0 + scol + 8);
        __syncthreads();
        *(uint4*)&As[srow * GLD + scol]     = a0;
        *(uint4*)&As[srow * GLD + scol + 8] = a1;
        *(uint4*)&Ws[srow * GLD + scol]     = w0;
        *(uint4*)&Ws[srow * GLD + scol + 8] = w1;
        __syncthreads();
        #pragma unroll
        for (int ks = 0; ks < 64; ks += 32) {
            U4B8 af0, af1, bf0, bf1;
            af0.u = *(const uint4*)&As[(wm +      fm) * GLD + ks + fq * 8];
            af1.u = *(const uint4*)&As[(wm + 16 + fm) * GLD + ks + fq * 8];
            bf0.u = *(const uint4*)&Ws[(wn +      fm) * GLD + ks + fq * 8];
            bf1.u = *(const uint4*)&Ws[(wn + 16 + fm) * GLD + ks + fq * 8];
            acc[0][0] = __builtin_amdgcn_mfma_f32_16x16x32_bf16(af0.b, bf0.b, acc[0][0], 0, 0, 0);
            acc[0][1] = __builtin_amdgcn_mfma_f32_16x16x32_bf16(af0.b, bf1.b, acc[0][1], 0, 0, 0);
            acc[1][0] = __builtin_amdgcn_mfma_f32_16x16x32_bf16(af1.b, bf0.b, acc[1][0], 0, 0, 0);
            acc[1][1] = __builtin_amdgcn_mfma_f32_16x16x32_bf16(af1.b, bf1.b, acc[1][1], 0, 0, 0);
        }
    }

    // C/D: col = lane&15, row = quad*4 + reg
    #pragma unroll
    for (int mt = 0; mt < 2; mt++) {
        #pragma unroll
        for (int nt = 0; nt < 2; nt++) {
            #pragma unroll
            for (int r = 0; r < 4; r++) {
                int row = m0 + wm + mt * 16 + fq * 4 + r;
                int col = j0 + wn + nt * 16 + fm;
                float val = acc[mt][nt][r] + qkv_b[col];
                int part = col >> 8;           // 0:q 1:k 2:v
                int head = (col >> 5) & 7;
                int d = col & 31;
                int b = row >> 10;
                int n = row & 1023;
                int bh = b * NH + head;
                if (part == 0)
                    qo[((size_t)bh * Ns + n) * DH + d] = f2bf(val * 0.0625f);
                else if (part == 1)
                    ko[((size_t)bh * Ns + n) * DH + d] = f2bf(val);
                else
                    vto[((size_t)bh * DH + d) * Ns + n] = f2bf(val);
            }
        }
    }
}

// ---------------------------------------------------------------------------
// Kernel 2: MFMA attention, in-register softmax (R7-verified math).
// XCD-aware swizzle: assuming round-robin blk->XCD (blk&7), batch b = blk&7
// so each XCD's resident blocks touch only its own 1 MB kb/vtb slice (fits
// the 4 MB XCD L2; cuts cross-L2/L3 refetch ~7x). Perf heuristic only.
// ---------------------------------------------------------------------------
__global__ __launch_bounds__(256)
void attn_mfma2(const unsigned short* __restrict__ qb, const unsigned short* __restrict__ kb,
                const unsigned short* __restrict__ vtb, unsigned short* __restrict__ aob)
{
    __shared__ unsigned short Pb[32 * PST];   // 14848 B
    __shared__ float pmax[2][32];
    __shared__ float psum[2][32];

    const int blk = blockIdx.x;          // 0..2047
    const int b   = blk & 7;             // XCD-locality: batch pinned to XCD
    const int u   = blk >> 3;            // 0..255
    const int h   = u & 7;
    const int hq  = u >> 3;              // 0..31
    const int bh  = b * NH + h;

    const int t   = threadIdx.x;
    const int lane = t & 63;
    const int w    = t >> 6;
    const int fm = lane & 15;
    const int fq = lane >> 4;

    int n0c = (hq - 3) * 32;
    n0c = n0c < 0 ? 0 : (n0c > Ns - 224 ? Ns - 224 : n0c);

    const int qbase = (w & 1) * 16;      // query 16-tile
    const int sel   = w >> 1;            // key-tile parity
    const int dbase = (w >> 1) * 16;     // PV dim-tile

    // V^T fragment prefetch (B-operand: n=dim, k=key)
    const unsigned short* vrow = vtb + ((size_t)bh * DH + dbase + fm) * Ns;
    uint4 vpre[7];
    #pragma unroll
    for (int i = 0; i < 7; i++)
        vpre[i] = *(const uint4*)(vrow + n0c + i * 32 + fq * 8);

    // Q fragment (A-operand)
    U4B8 qa;
    qa.u = *(const uint4*)(qb + ((size_t)bh * Ns + hq * 32 + qbase + fm) * DH + fq * 8);

    // S = Q.K^T in C-layout registers (key = kt*16+fm, query = qbase+fq*4+r)
    f32x4 sv[7];
    #pragma unroll
    for (int i = 0; i < 7; i++) {
        int kt = sel + 2 * i;
        U4B8 kf;
        kf.u = *(const uint4*)(kb + ((size_t)bh * Ns + n0c + kt * 16 + fm) * DH + fq * 8);
        sv[i] = __builtin_amdgcn_mfma_f32_16x16x32_bf16(qa.b, kf.b, (f32x4){0.f,0.f,0.f,0.f}, 0, 0, 0);
    }

    // Inline window mask + per-query local max
    float mx[4] = {-INFINITY, -INFINITY, -INFINITY, -INFINITY};
    #pragma unroll
    for (int i = 0; i < 7; i++) {
        int g = n0c + (sel + 2 * i) * 16 + fm;
        int gh = g >> 5, gw = g & 31;
        int dhh = gh - hq;
        bool okh = (dhh >= -3) && (dhh <= 3);
        #pragma unroll
        for (int r = 0; r < 4; r++) {
            int qc = qbase + fq * 4 + r;
            int dww = gw - qc;
            bool ok = okh && (dww >= -5) && (dww <= 5);
            float s = ok ? sv[i][r] : -INFINITY;
            sv[i][r] = s;
            mx[r] = fmaxf(mx[r], s);
        }
    }
    #pragma unroll
    for (int r = 0; r < 4; r++)
        #pragma unroll
        for (int m = 1; m < 16; m <<= 1)
            mx[r] = fmaxf(mx[r], __shfl_xor(mx[r], m));
    if (fm == 0) {
        #pragma unroll
        for (int r = 0; r < 4; r++)
            pmax[sel][qbase + fq * 4 + r] = mx[r];
    }
    __syncthreads();

    float M[4];
    #pragma unroll
    for (int r = 0; r < 4; r++) {
        int qc = qbase + fq * 4 + r;
        M[r] = fmaxf(pmax[0][qc], pmax[1][qc]);
    }

    float sm[4] = {0.f, 0.f, 0.f, 0.f};
    #pragma unroll
    for (int i = 0; i < 7; i++) {
        int kt = sel + 2 * i;
        #pragma unroll
        for (int r = 0; r < 4; r++) {
            float p = __expf(sv[i][r] - M[r]);     // -inf -> 0
            unsigned short pu = f2bf(p);
            Pb[(qbase + fq * 4 + r) * PST + kt * 16 + fm] = pu;
            sm[r] += bf2f(pu);
        }
    }
    #pragma unroll
    for (int r = 0; r < 4; r++)
        #pragma unroll
        for (int m = 1; m < 16; m <<= 1)
            sm[r] += __shfl_xor(sm[r], m);
    if (fm == 0) {
        #pragma unroll
        for (int r = 0; r < 4; r++)
            psum[sel][qbase + fq * 4 + r] = sm[r];
    }
    __syncthreads();   // P complete + psum visible

    // O = P.V
    f32x4 acc = (f32x4){0.f, 0.f, 0.f, 0.f};
    #pragma unroll
    for (int i = 0; i < 7; i++) {
        U4B8 pa, vb;
        pa.u = *(const uint4*)&Pb[(qbase + fm) * PST + i * 32 + fq * 8];
        vb.u = vpre[i];
        acc = __builtin_amdgcn_mfma_f32_16x16x32_bf16(pa.b, vb.b, acc, 0, 0, 0);
    }

    #pragma unroll
    for (int r = 0; r < 4; r++) {
        int qq = qbase + fq * 4 + r;
        float inv = 1.f / (psum[0][qq] + psum[1][qq]);
        aob[((size_t)(b * Ns) + hq * 32 + qq) * Es + h * DH + dbase + fm] = f2bf(acc[r] * inv);
    }
}

// ---------------------------------------------------------------------------
// Kernel 3: proj GEMM, bf16 inputs (aob, pwb), fp32 out. 64x64 tile, BK=64.
// ---------------------------------------------------------------------------
__global__ __launch_bounds__(256, 4)
void proj_gemm(const unsigned short* __restrict__ A, const unsigned short* __restrict__ Wb,
               const float* __restrict__ bias, float* __restrict__ out)
{
    __shared__ unsigned short As[64 * GLD];
    __shared__ unsigned short Ws[64 * GLD];

    const int t = threadIdx.x;
    const int m0 = (blockIdx.x & 127) * 64;
    const int j0 = (blockIdx.x >> 7) * 64;

    const int srow = t >> 2;
    const int scol = (t & 3) * 16;

    const int lane = t & 63;
    const int wave = t >> 6;
    const int wm = (wave & 1) * 32;
    const int wn = (wave >> 1) * 32;
    const int fm = lane & 15;
    const int fq = lane >> 4;

    f32x4 acc[2][2];
    #pragma unroll
    for (int i = 0; i < 2; i++)
        #pragma unroll
        for (int j = 0; j < 2; j++)
            acc[i][j] = (f32x4){0.f, 0.f, 0.f, 0.f};

    const unsigned short* Arow = A + (size_t)(m0 + srow) * Es;
    const unsigned short* Wrow = Wb + (size_t)(j0 + srow) * Es;

    for (int k0 = 0; k0 < Es; k0 += 64) {
        uint4 a0 = *(const uint4*)(Arow + k0 + scol);
        uint4 a1 = *(const uint4*)(Arow + k0 + scol + 8);
        uint4 w0 = *(const uint4*)(Wrow + k0 + scol);
        uint4 w1 = *(const uint4*)(Wrow + k0 + scol + 8);
        __syncthreads();
        *(uint4*)&As[srow * GLD + scol]     = a0;
        *(uint4*)&As[srow * GLD + scol + 8] = a1;
        *(uint4*)&Ws[srow * GLD + scol]     = w0;
        *(uint4*)&Ws[srow * GLD + scol + 8] = w1;
        __syncthreads();
        #pragma unroll
        for (int ks = 0; ks < 64; ks += 32) {
            U4B8 af0, af1, bf0, bf1;
            af0.u = *(const uint4*)&As[(wm +      fm) * GLD + ks + fq * 8];
            af1.u = *(const uint4*)&As[(wm + 16 + fm) * GLD + ks + fq * 8];
            bf0.u = *(const uint4*)&Ws[(wn +      fm) * GLD + ks + fq * 8];
            bf1.u = *(const uint4*)&Ws[(wn + 16 + fm) * GLD + ks + fq * 8];
            acc[0][0] = __builtin_amdgcn_mfma_f32_16x16x32_bf16(af0.b, bf0.b, acc[0][0], 0, 0, 0);
            acc[0][1] = __builtin_amdgcn_mfma_f32_16x16x32_bf16(af0.b, bf1.b, acc[0][1], 0, 0, 0);
            acc[1][0] = __builtin_amdgcn_mfma_f32_16x16x32_bf16(af1.b, bf0.b, acc[1][0], 0, 0, 0);
            acc[1][1] = __builtin_amdgcn_mfma_f32_16x16x32_bf16(af1.b, bf1.b, acc[1][1], 0, 0, 0);
        }
    }

    #pragma unroll
    for (int mt = 0; mt < 2; mt++) {
        #pragma unroll
        for (int nt = 0; nt < 2; nt++) {
            #pragma unroll
            for (int r = 0; r < 4; r++) {
                int row = m0 + wm + mt * 16 + fq * 4 + r;
                int col = j0 + wn + nt * 16 + fm;
                out[(size_t)row * Es + col] = acc[mt][nt][r] + bias[col];
            }
        }
    }
}

extern "C" void kernel_launch(void* const* d_in, const int* in_sizes, int n_in,
                              void* d_out, int out_size, void* d_ws, size_t ws_size,
                              hipStream_t stream) {
    const float* x      = (const float*)d_in[0];  // [B,N,E]
    const float* qkv_w  = (const float*)d_in[1];  // [3E,E]
    const float* qkv_b  = (const float*)d_in[2];  // [3E]
    const float* proj_w = (const float*)d_in[3];  // [E,E]
    const float* proj_b = (const float*)d_in[4];  // [E]
    float* out = (float*)d_out;                   // [B,N,E]

    unsigned short* xb  = (unsigned short*)d_ws;  // NX bf16
    unsigned short* wqb = xb + NX;                // NQ bf16
    unsigned short* pwb = wqb + NQ;               // NP bf16
    unsigned short* qb  = pwb + NP;               // NX bf16 (q, scaled)
    unsigned short* kb  = qb + NX;                // NX bf16
    unsigned short* vtb = kb + NX;                // NX bf16 (transposed)
    unsigned short* aob = vtb + NX;               // NX bf16 (attn out)

    cast_all<<<dim3((NX + NQ + NP) / 8 / 256), dim3(256), 0, stream>>>(
        x, qkv_w, proj_w, xb, wqb, pwb);

    qkv_gemm<<<dim3(1536), dim3(256), 0, stream>>>(xb, wqb, qkv_b, qb, kb, vtb);

    attn_mfma2<<<dim3(Bb * NH * 32), dim3(256), 0, stream>>>(qb, kb, vtb, aob);

    proj_gemm<<<dim3(Mrows / 64 * (Es / 64)), dim3(256), 0, stream>>>(
        aob, pwb, proj_b, out);
}